// Round 4
// baseline (449.728 us; speedup 1.0000x reference)
//
#include <hip/hip_runtime.h>
#include <cstdint>

#define N_NODES 4096
#define DM 64
#define K_DIM 8192   // S*N
#define M_DIM 2048   // B*DM

typedef uint8_t u8;
using i32x8   = __attribute__((ext_vector_type(8))) int;
using floatx4 = __attribute__((ext_vector_type(4))) float;

#define GLOAD_LDS16(gp, lp)                                                     \
  __builtin_amdgcn_global_load_lds(                                             \
      reinterpret_cast<const __attribute__((address_space(1))) void*>(          \
          reinterpret_cast<uintptr_t>(gp)),                                     \
      reinterpret_cast<__attribute__((address_space(3))) void*>(                \
          (uint32_t)reinterpret_cast<uintptr_t>(lp)),                           \
      16, 0, 0)

// pack 4 floats -> 4 fp8(e4m3) bytes in one int
__device__ inline int pk_fp8x4(float f0, float f1, float f2, float f3) {
  int r = __builtin_amdgcn_cvt_pk_fp8_f32(f0, f1, 0, false);   // bytes 0,1
  r     = __builtin_amdgcn_cvt_pk_fp8_f32(f2, f3, r, true);    // bytes 2,3
  return r;
}

// ---------------- kernel 0: fold W_lin_a @ W_mlp -> WLW[64][130]; b2 = W_lin_a@bmlp+blin
__global__ __launch_bounds__(256) void k_fold(const float* __restrict__ Wmlp,
                                              const float* __restrict__ bmlp,
                                              const float* __restrict__ Wlin,
                                              const float* __restrict__ blin,
                                              float* __restrict__ WLW,
                                              float* __restrict__ b2) {
  __shared__ float sWl[64 * 64];    // Wlin[:, :64]
  __shared__ float sWm[64 * 130];   // Wmlp
  for (uint32_t t = threadIdx.x; t < 64 * 128; t += 256) {
    uint32_t d = t >> 7, c = t & 127u;
    if (c < 64u) sWl[d * 64 + c] = Wlin[t];
  }
  for (uint32_t t = threadIdx.x; t < 64 * 130; t += 256) sWm[t] = Wmlp[t];
  __syncthreads();
  for (uint32_t o = threadIdx.x; o < 64 * 130; o += 256) {
    uint32_t dp = o / 130u, sc = o % 130u;
    float s = 0.f;
#pragma unroll 8
    for (int d = 0; d < 64; ++d) s += sWl[dp * 64 + d] * sWm[d * 130 + sc];
    WLW[o] = s;
  }
  if (threadIdx.x < 64) {
    float s = blin[threadIdx.x];
#pragma unroll 8
    for (int d = 0; d < 64; ++d) s += sWl[threadIdx.x * 64 + d] * bmlp[d];
    b2[threadIdx.x] = s;
  }
}

// ---------------- kernel 1: adj f32 [S][N][N] -> BT8 fp8 [N][S*N], value*4096
// lean: no LDS, 8 elems/thread
__global__ __launch_bounds__(256) void k_adj2bt(const float* __restrict__ adj,
                                                u8* __restrict__ BT8) {
  uint32_t idx = blockIdx.x * 256u + threadIdx.x;     // over S*N*(N/8) = 4,194,304
  uint32_t v8 = idx & 511u;
  uint32_t w  = (idx >> 9) & 4095u;
  uint32_t s  = idx >> 21;
  const float4* src = reinterpret_cast<const float4*>(adj) + (size_t)idx * 2;
  float4 f0 = src[0], f1 = src[1];
  uint2 pk;
  pk.x = (uint32_t)pk_fp8x4(f0.x * 4096.f, f0.y * 4096.f, f0.z * 4096.f, f0.w * 4096.f);
  pk.y = (uint32_t)pk_fp8x4(f1.x * 4096.f, f1.y * 4096.f, f1.z * 4096.f, f1.w * 4096.f);
  *reinterpret_cast<uint2*>(BT8 + ((size_t)w * K_DIM + s * N_NODES + v8 * 8)) = pk;
}

// ---------------- kernel 2: A8[(b*64+d')][s*N+v] = fp8( sum_c WLW[d'][s*65+c]*x_in[b][c][v] )
// thread owns 4 v x 16 d'
__global__ __launch_bounds__(256) void k_mkA(const float* __restrict__ x,
                                             const float* __restrict__ h,
                                             const float* __restrict__ WLW,
                                             u8* __restrict__ A8) {
  __shared__ __align__(16) float Ws[DM * 68];
  uint32_t bi = blockIdx.x;                           // 32 b x 2 s x 16 v0 = 1024
  uint32_t v0 = (bi & 15u) * 256u;
  uint32_t s  = (bi >> 4) & 1u;
  uint32_t b  = bi >> 5;
  for (uint32_t t = threadIdx.x; t < DM * 68; t += 256) {
    uint32_t d = t / 68u, c = t % 68u;
    Ws[t] = (c < 65u) ? WLW[d * 130u + s * 65u + c] : 0.f;
  }
  __syncthreads();

  const uint32_t tv = threadIdx.x & 63u;
  const uint32_t td = threadIdx.x >> 6;               // wave-uniform -> LDS broadcast
  const uint32_t v  = v0 + tv * 4u;

  float acc[16][4];
#pragma unroll
  for (int d = 0; d < 16; ++d)
#pragma unroll
    for (int k = 0; k < 4; ++k) acc[d][k] = 0.f;

  for (int c0 = 0; c0 < 64; c0 += 4) {
    float4 in4[4];
#pragma unroll
    for (int j = 0; j < 4; ++j) {
      int c = c0 + j;
      const float* src = (c == 0) ? (x + (size_t)b * N_NODES + v)
                                  : (h + ((size_t)b * DM + (c - 1)) * N_NODES + v);
      in4[j] = *reinterpret_cast<const float4*>(src);
    }
#pragma unroll
    for (int d = 0; d < 16; ++d) {
      const float4 w4 = *reinterpret_cast<const float4*>(&Ws[(td * 16 + d) * 68 + c0]);
      acc[d][0] += w4.x * in4[0].x + w4.y * in4[1].x + w4.z * in4[2].x + w4.w * in4[3].x;
      acc[d][1] += w4.x * in4[0].y + w4.y * in4[1].y + w4.z * in4[2].y + w4.w * in4[3].y;
      acc[d][2] += w4.x * in4[0].z + w4.y * in4[1].z + w4.z * in4[2].z + w4.w * in4[3].z;
      acc[d][3] += w4.x * in4[0].w + w4.y * in4[1].w + w4.z * in4[2].w + w4.w * in4[3].w;
    }
  }
  { // tail channel c=64 -> h row 63
    float4 in4 = *reinterpret_cast<const float4*>(h + ((size_t)b * DM + 63) * N_NODES + v);
#pragma unroll
    for (int d = 0; d < 16; ++d) {
      float w = Ws[(td * 16 + d) * 68 + 64];
      acc[d][0] += w * in4.x; acc[d][1] += w * in4.y;
      acc[d][2] += w * in4.z; acc[d][3] += w * in4.w;
    }
  }
#pragma unroll
  for (int d = 0; d < 16; ++d) {
    int p = pk_fp8x4(acc[d][0], acc[d][1], acc[d][2], acc[d][3]);
    *reinterpret_cast<int*>(A8 + (size_t)(b * DM + td * 16 + d) * K_DIM + s * N_NODES + v) = p;
  }
}

// ---------------- kernel 3: C_z[m][n] = sum_{k half z} A8[m][k]*BT8[n][k]
// MX-fp8 MFMA 16x16x128, scale 1.0; 128x128 tile, BK=128, split-K=2
__global__ void k_gemm(const u8* __restrict__ A, const u8* __restrict__ BT,
                       float* __restrict__ C) {
  __shared__ __align__(32) u8 As[4][128][32];   // 16 KB
  __shared__ __align__(32) u8 Bs[4][128][32];   // 16 KB
  const int tid  = threadIdx.x;
  const int lane = tid & 63;
  const int wave = tid >> 6;
  const int wr = wave >> 1, wc = wave & 1;      // 2x2 wave grid, 64x64 each
  const int m0 = blockIdx.y * 128, n0 = blockIdx.x * 128;
  const size_t kb = (size_t)blockIdx.z * 4096;

  const int srow = lane >> 1;
  const int shalf = (lane & 1) * 16;
  const u8* Ag = A  + (size_t)(m0 + wave * 32 + srow) * K_DIM + kb + shalf;
  const u8* Bg = BT + (size_t)(n0 + wave * 32 + srow) * K_DIM + kb + shalf;
  u8* AsB[4]; u8* BsB[4];
#pragma unroll
  for (int q = 0; q < 4; ++q) { AsB[q] = &As[q][wave * 32][0]; BsB[q] = &Bs[q][wave * 32][0]; }

  floatx4 acc[4][4];
#pragma unroll
  for (int i = 0; i < 4; ++i)
#pragma unroll
    for (int j = 0; j < 4; ++j) acc[i][j] = (floatx4){0.f, 0.f, 0.f, 0.f};

  const int fm = lane & 15;
  const int fq = lane >> 4;
  const int SC1 = 0x7F7F7F7F;    // e8m0 scale = 1.0

  for (int k0 = 0; k0 < 4096; k0 += 128) {
#pragma unroll
    for (int q = 0; q < 4; ++q) GLOAD_LDS16(Ag + k0 + q * 32, AsB[q]);
#pragma unroll
    for (int q = 0; q < 4; ++q) GLOAD_LDS16(Bg + k0 + q * 32, BsB[q]);
    __syncthreads();

    i32x8 af[4], bfr[4];
#pragma unroll
    for (int i = 0; i < 4; ++i)
      af[i] = *reinterpret_cast<const i32x8*>(&As[fq][wr * 64 + i * 16 + fm][0]);
#pragma unroll
    for (int j = 0; j < 4; ++j)
      bfr[j] = *reinterpret_cast<const i32x8*>(&Bs[fq][wc * 64 + j * 16 + fm][0]);
#pragma unroll
    for (int i = 0; i < 4; ++i)
#pragma unroll
      for (int j = 0; j < 4; ++j)
        acc[i][j] = __builtin_amdgcn_mfma_scale_f32_16x16x128_f8f6f4(
            af[i], bfr[j], acc[i][j], 0, 0, 0, SC1, 0, SC1);
    __syncthreads();
  }

  float* Cz = C + (size_t)blockIdx.z * M_DIM * N_NODES;
  const int cr = (lane >> 4) * 4;
  const int cc = lane & 15;
#pragma unroll
  for (int i = 0; i < 4; ++i)
#pragma unroll
    for (int j = 0; j < 4; ++j) {
      float* Cp = Cz + (size_t)(m0 + wr * 64 + i * 16 + cr) * N_NODES
                     + (n0 + wc * 64 + j * 16 + cc);
#pragma unroll
      for (int r = 0; r < 4; ++r) Cp[(size_t)r * N_NODES] = acc[i][j][r];
    }
}

// ---------------- kernel 4: epilogue
// out2[b,d',n] = (C0+C1)[b*64+d'][n]/4096 + b2[d'] + sum_j Wlin[d'][64+j]*h[b][j][n]
// out1 = [PReLU(out2); h], out0 = Wread . out1 + bread
__global__ __launch_bounds__(256) void k_epilogue(
    const float* __restrict__ C0, const float* __restrict__ C1,
    const float* __restrict__ h, const float* __restrict__ Wlin,
    const float* __restrict__ b2g, const float* __restrict__ Wread,
    const float* __restrict__ bread, const float* __restrict__ pa,
    float* __restrict__ out0, float* __restrict__ out1) {
  __shared__ __align__(16) float sWb[DM * 68];   // Wlin[:,64:], stride 68
  __shared__ float sb2[DM], sWr[128];
  __shared__ float psum[3 * 256];
  for (uint32_t t = threadIdx.x; t < DM * 64; t += 256) {
    uint32_t d = t >> 6, c = t & 63u;
    sWb[d * 68 + c] = Wlin[d * 128 + 64 + c];
  }
  if (threadIdx.x < DM) sb2[threadIdx.x] = b2g[threadIdx.x];
  if (threadIdx.x < 128) sWr[threadIdx.x] = Wread[threadIdx.x];
  __syncthreads();

  uint32_t bi = blockIdx.x;                  // 32 b x 16 n0 = 512 blocks
  uint32_t n0 = (bi & 15u) * 256u;
  uint32_t b  = bi >> 4;
  const uint32_t tv = threadIdx.x & 63u;
  const uint32_t td = threadIdx.x >> 6;
  const uint32_t n  = n0 + tv * 4u;
  const float KS = 1.0f / 4096.0f;

  float acc[16][4];
#pragma unroll
  for (int d = 0; d < 16; ++d) {
    size_t off = ((size_t)b * DM + td * 16 + d) * N_NODES + n;
    float4 v0 = *reinterpret_cast<const float4*>(C0 + off);
    float4 v1 = *reinterpret_cast<const float4*>(C1 + off);
    float bb = sb2[td * 16 + d];
    acc[d][0] = (v0.x + v1.x) * KS + bb;
    acc[d][1] = (v0.y + v1.y) * KS + bb;
    acc[d][2] = (v0.z + v1.z) * KS + bb;
    acc[d][3] = (v0.w + v1.w) * KS + bb;
  }

  for (int c0 = 0; c0 < 64; c0 += 4) {       // h-half of W_lin
    float4 in4[4];
#pragma unroll
    for (int j = 0; j < 4; ++j)
      in4[j] = *reinterpret_cast<const float4*>(h + ((size_t)b * DM + (c0 + j)) * N_NODES + n);
#pragma unroll
    for (int d = 0; d < 16; ++d) {
      const float4 w4 = *reinterpret_cast<const float4*>(&sWb[(td * 16 + d) * 68 + c0]);
      acc[d][0] += w4.x * in4[0].x + w4.y * in4[1].x + w4.z * in4[2].x + w4.w * in4[3].x;
      acc[d][1] += w4.x * in4[0].y + w4.y * in4[1].y + w4.z * in4[2].y + w4.w * in4[3].y;
      acc[d][2] += w4.x * in4[0].z + w4.y * in4[1].z + w4.z * in4[2].z + w4.w * in4[3].z;
      acc[d][3] += w4.x * in4[0].w + w4.y * in4[1].w + w4.z * in4[2].w + w4.w * in4[3].w;
    }
  }

  const float a = pa[0];
  float r[4] = {0.f, 0.f, 0.f, 0.f};
  float* o1b = out1 + (size_t)b * 128 * N_NODES + n;
#pragma unroll
  for (int d = 0; d < 16; ++d) {
    float4 o2;
    o2.x = acc[d][0] >= 0.f ? acc[d][0] : a * acc[d][0];
    o2.y = acc[d][1] >= 0.f ? acc[d][1] : a * acc[d][1];
    o2.z = acc[d][2] >= 0.f ? acc[d][2] : a * acc[d][2];
    o2.w = acc[d][3] >= 0.f ? acc[d][3] : a * acc[d][3];
    *reinterpret_cast<float4*>(o1b + (size_t)(td * 16 + d) * N_NODES) = o2;
    float wr = sWr[td * 16 + d];
    r[0] += wr * o2.x; r[1] += wr * o2.y; r[2] += wr * o2.z; r[3] += wr * o2.w;
  }
#pragma unroll
  for (int d = 0; d < 16; ++d) {             // copy h -> out1[64+...] (L2-hot reload)
    float4 hv = *reinterpret_cast<const float4*>(h + ((size_t)b * DM + td * 16 + d) * N_NODES + n);
    *reinterpret_cast<float4*>(o1b + (size_t)(64 + td * 16 + d) * N_NODES) = hv;
    float wr = sWr[64 + td * 16 + d];
    r[0] += wr * hv.x; r[1] += wr * hv.y; r[2] += wr * hv.z; r[3] += wr * hv.w;
  }
  if (td > 0) {
#pragma unroll
    for (int k = 0; k < 4; ++k) psum[(td - 1) * 256 + tv * 4 + k] = r[k];
  }
  __syncthreads();
  if (td == 0) {
    float br = bread[0];
#pragma unroll
    for (int k = 0; k < 4; ++k)
      r[k] += br + psum[tv * 4 + k] + psum[256 + tv * 4 + k] + psum[512 + tv * 4 + k];
    float4 o0; o0.x = r[0]; o0.y = r[1]; o0.z = r[2]; o0.w = r[3];
    *reinterpret_cast<float4*>(out0 + (size_t)b * N_NODES + n) = o0;
  }
}

extern "C" void kernel_launch(void* const* d_in, const int* in_sizes, int n_in,
                              void* d_out, int out_size, void* d_ws, size_t ws_size,
                              hipStream_t stream) {
  const float* x     = (const float*)d_in[0];
  const float* h     = (const float*)d_in[1];
  const float* adj   = (const float*)d_in[2];
  const float* Wmlp  = (const float*)d_in[3];
  const float* bmlp  = (const float*)d_in[4];
  const float* Wlin  = (const float*)d_in[5];
  const float* blin  = (const float*)d_in[6];
  const float* Wread = (const float*)d_in[7];
  const float* bread = (const float*)d_in[8];
  const float* pa    = (const float*)d_in[9];

  char* ws = (char*)d_ws;
  u8*    Abuf  = (u8*)ws;                        // 2048*8192   = 16 MiB
  u8*    BTbuf = (u8*)(ws + (16ull << 20));      // 4096*8192   = 32 MiB
  float* Cbuf  = (float*)(ws + (48ull << 20));   // 2 x 32 MiB (split-K partials)
  float* WLW   = (float*)(ws + (112ull << 20));  // 64*130 f32
  float* b2    = (float*)(ws + (112ull << 20) + 65536);
  float* out0 = (float*)d_out;                   // [32,1,4096]
  float* out1 = out0 + 131072;                   // [32,128,4096]

  hipLaunchKernelGGL(k_fold,     dim3(1),         dim3(256), 0, stream,
                     Wmlp, bmlp, Wlin, blin, WLW, b2);
  hipLaunchKernelGGL(k_adj2bt,   dim3(16384),     dim3(256), 0, stream, adj, BTbuf);
  hipLaunchKernelGGL(k_mkA,      dim3(1024),      dim3(256), 0, stream, x, h, WLW, Abuf);
  hipLaunchKernelGGL(k_gemm,     dim3(32, 16, 2), dim3(256), 0, stream, Abuf, BTbuf, Cbuf);
  hipLaunchKernelGGL(k_epilogue, dim3(512),       dim3(256), 0, stream,
                     Cbuf, Cbuf + (size_t)M_DIM * N_NODES, h, Wlin, b2,
                     Wread, bread, pa, out0, out1);
}